// Round 9
// baseline (539.294 us; speedup 1.0000x reference)
//
#include <hip/hip_runtime.h>
#include <stdint.h>

typedef __attribute__((ext_vector_type(8))) short short8;   // 8 x bf16 MFMA operand
typedef __attribute__((ext_vector_type(4))) float floatx4;  // MFMA accumulator

#define DEV __device__ __forceinline__

DEV unsigned short f2bf(float x) {  // fp32 -> bf16 RNE (epilogue-only; hot paths use pkbf)
  unsigned u = __float_as_uint(x);
  u += 0x7fffu + ((u >> 16) & 1u);
  return (unsigned short)(u >> 16);
}

// pack two fp32 -> two bf16 (round-half-up) in 3 VALU: 2 adds + v_perm
DEV unsigned pkbf(float hi, float lo) {
  return __builtin_amdgcn_perm(__float_as_uint(hi) + 0x8000u,
                               __float_as_uint(lo) + 0x8000u, 0x07060302u);
}

DEV void load_lds16(const unsigned short* g, unsigned short* l) {
  __builtin_amdgcn_global_load_lds(
      (const __attribute__((address_space(1))) void*)g,
      (__attribute__((address_space(3))) void*)l, 16, 0, 0);
}

DEV void lds_fence() { asm volatile("" ::: "memory"); }  // wave-private LDS RAW/WAR ordering

// ---------------- one-shot fp32 -> bf16 of all 7 tensors ----------------
__global__ void cvt_all(const float* __restrict__ Wq, const float* __restrict__ Wk,
                        const float* __restrict__ Wv, const float* __restrict__ Wo,
                        const float* __restrict__ Xq, const float* __restrict__ Xk,
                        const float* __restrict__ Xv,
                        unsigned short* __restrict__ Wb, unsigned short* __restrict__ XqB,
                        unsigned short* __restrict__ XkB, unsigned short* __restrict__ XvB) {
  int bid = blockIdx.x;
  const float* src;
  unsigned short* dst;
  int off;
  if (bid < 4096) {
    int sel = bid >> 10;
    src = sel == 0 ? Wq : sel == 1 ? Wk : sel == 2 ? Wv : Wo;
    dst = Wb + (size_t)sel * 1048576;
    off = bid & 1023;
  } else {
    bid -= 4096;
    int sel = bid >> 13;
    src = sel == 0 ? Xq : sel == 1 ? Xk : Xv;
    dst = sel == 0 ? XqB : sel == 1 ? XkB : XvB;
    off = bid & 8191;
  }
  int i = (off * 256 + threadIdx.x) * 4;
  float4 v = *(const float4*)(src + i);
  uint2 o;
  o.x = pkbf(v.y, v.x);
  o.y = pkbf(v.w, v.z);
  *(uint2*)(dst + i) = o;
}

// ---------------- fused QKV projection: all-bf16 async staging, grid (8,64,3) ----------------
// z=0: Qp[b,h,s,64] = (q@Wq^T+bq) * SCQ   z=1: Kp = k@Wk^T+bk
// z=2: VTp[b,h,64,s] = (v@Wv^T+bv)^T (A/B operand roles swapped)
#define SCQ (0.125f * 1.44269504089f)
__global__ __launch_bounds__(256, 3) void qkv_gemm(
    const unsigned short* __restrict__ XqB, const unsigned short* __restrict__ XkB,
    const unsigned short* __restrict__ XvB,
    const unsigned short* __restrict__ Wb,
    const float* __restrict__ bq, const float* __restrict__ bk, const float* __restrict__ bv,
    unsigned short* __restrict__ Qp, unsigned short* __restrict__ Kp,
    unsigned short* __restrict__ VTp) {
  __shared__ alignas(16) unsigned short Xs[128 * 32];
  __shared__ alignas(16) unsigned short Ws[128 * 32];
  const int z = blockIdx.z;
  const unsigned short* X = z == 0 ? XqB : z == 1 ? XkB : XvB;
  const unsigned short* W = Wb + (size_t)z * 1048576;
  const float* bias = z == 0 ? bq : z == 1 ? bk : bv;

  const int tid = threadIdx.x;
  const int lane = tid & 63, wave = tid >> 6;
  const int lcol = lane & 15, quad = lane >> 4;
  const int wo = blockIdx.x * 128;  // d origin (weight rows)
  const int xo = blockIdx.y * 128;  // s origin (input rows)
  const int wm = (wave & 1) * 64;
  const int wn = (wave >> 1) * 64;

  floatx4 acc[4][4];
  for (int mi = 0; mi < 4; ++mi)
    for (int ni = 0; ni < 4; ++ni)
      for (int r = 0; r < 4; ++r) acc[mi][ni][r] = 0.f;

  const unsigned short* Abuf = (z < 2) ? Xs : Ws;  // MFMA A operand rows (m)
  const unsigned short* Bbuf = (z < 2) ? Ws : Xs;  // MFMA B operand rows (n)

  for (int kt = 0; kt < 32; ++kt) {
    const int k0 = kt * 32;
    int c = tid;
    load_lds16(W + (size_t)(wo + (c >> 2)) * 1024 + k0 + (c & 3) * 8, Ws + c * 8);
    load_lds16(X + (size_t)(xo + (c >> 2)) * 1024 + k0 + (c & 3) * 8, Xs + c * 8);
    c = tid + 256;
    load_lds16(W + (size_t)(wo + (c >> 2)) * 1024 + k0 + (c & 3) * 8, Ws + c * 8);
    load_lds16(X + (size_t)(xo + (c >> 2)) * 1024 + k0 + (c & 3) * 8, Xs + c * 8);
    __syncthreads();
    short8 af[4], bf[4];
#pragma unroll
    for (int mi = 0; mi < 4; ++mi)
      af[mi] = *(const short8*)(Abuf + (wm + mi * 16 + lcol) * 32 + quad * 8);
#pragma unroll
    for (int ni = 0; ni < 4; ++ni)
      bf[ni] = *(const short8*)(Bbuf + (wn + ni * 16 + lcol) * 32 + quad * 8);
#pragma unroll
    for (int mi = 0; mi < 4; ++mi)
#pragma unroll
      for (int ni = 0; ni < 4; ++ni)
        acc[mi][ni] = __builtin_amdgcn_mfma_f32_16x16x32_bf16(af[mi], bf[ni], acc[mi][ni], 0, 0, 0);
    __syncthreads();
  }

  if (z < 2) {  // C[m=s][n=d] -> head-split [B,H,S,64]
    unsigned short* Out = z == 0 ? Qp : Kp;
    const float scl = z == 0 ? SCQ : 1.f;
#pragma unroll
    for (int ni = 0; ni < 4; ++ni) {
      int col = wo + wn + ni * 16 + lcol;
      float bvx = bias[col];
      int h = col >> 6, d = col & 63;
#pragma unroll
      for (int mi = 0; mi < 4; ++mi) {
        int rbase = xo + wm + mi * 16 + quad * 4;
#pragma unroll
        for (int r = 0; r < 4; ++r) {
          int grow = rbase + r;            // = b*2048 + s
          int bb = grow >> 11, s = grow & 2047;
          Out[((size_t)(bb * 16 + h) * 2048 + s) * 64 + d] = f2bf((acc[mi][ni][r] + bvx) * scl);
        }
      }
    }
  } else {  // C[m=d][n=s] -> V^T [B,H,64,S]
#pragma unroll
    for (int mi = 0; mi < 4; ++mi) {
      int dbase = wo + wm + mi * 16 + quad * 4;
#pragma unroll
      for (int r = 0; r < 4; ++r) {
        int dg = dbase + r;
        float bvx = bias[dg];
        int h = dg >> 6, dk = dg & 63;
#pragma unroll
        for (int ni = 0; ni < 4; ++ni) {
          int sg = xo + wn + ni * 16 + lcol;  // = b*2048 + s
          int bb = sg >> 11, ss = sg & 2047;
          VTp[((size_t)(bb * 16 + h) * 64 + dk) * 2048 + ss] = f2bf(acc[mi][ni][r] + bvx);
        }
      }
    }
  }
}

// ---------------- final O-projection: fp32 out ----------------
__global__ __launch_bounds__(256, 3) void gemm_o(
    const unsigned short* __restrict__ A, const unsigned short* __restrict__ Bw,
    const float* __restrict__ bias, float* __restrict__ Out) {
  __shared__ alignas(16) unsigned short As[128 * 32];
  __shared__ alignas(16) unsigned short Bs[128 * 32];
  const int tid = threadIdx.x;
  const int lane = tid & 63, wave = tid >> 6;
  const int lcol = lane & 15, quad = lane >> 4;
  const int n0 = blockIdx.x * 128;
  const int m0 = blockIdx.y * 128;
  const int wm = (wave & 1) * 64;
  const int wn = (wave >> 1) * 64;

  floatx4 acc[4][4];
  for (int mi = 0; mi < 4; ++mi)
    for (int ni = 0; ni < 4; ++ni)
      for (int r = 0; r < 4; ++r) acc[mi][ni][r] = 0.f;

  for (int kt = 0; kt < 32; ++kt) {
    const int k0 = kt * 32;
    int c = tid;
    load_lds16(Bw + (size_t)(n0 + (c >> 2)) * 1024 + k0 + (c & 3) * 8, Bs + c * 8);
    load_lds16(A  + (size_t)(m0 + (c >> 2)) * 1024 + k0 + (c & 3) * 8, As + c * 8);
    c = tid + 256;
    load_lds16(Bw + (size_t)(n0 + (c >> 2)) * 1024 + k0 + (c & 3) * 8, Bs + c * 8);
    load_lds16(A  + (size_t)(m0 + (c >> 2)) * 1024 + k0 + (c & 3) * 8, As + c * 8);
    __syncthreads();
    short8 af[4], bf[4];
#pragma unroll
    for (int mi = 0; mi < 4; ++mi)
      af[mi] = *(const short8*)(As + (wm + mi * 16 + lcol) * 32 + quad * 8);
#pragma unroll
    for (int ni = 0; ni < 4; ++ni)
      bf[ni] = *(const short8*)(Bs + (wn + ni * 16 + lcol) * 32 + quad * 8);
#pragma unroll
    for (int mi = 0; mi < 4; ++mi)
#pragma unroll
      for (int ni = 0; ni < 4; ++ni)
        acc[mi][ni] = __builtin_amdgcn_mfma_f32_16x16x32_bf16(af[mi], bf[ni], acc[mi][ni], 0, 0, 0);
    __syncthreads();
  }
#pragma unroll
  for (int ni = 0; ni < 4; ++ni) {
    int col = n0 + wn + ni * 16 + lcol;
    float bv = bias[col];
#pragma unroll
    for (int mi = 0; mi < 4; ++mi) {
      int rbase = m0 + wm + mi * 16 + quad * 4;
#pragma unroll
      for (int r = 0; r < 4; ++r)
        Out[(size_t)(rbase + r) * 1024 + col] = acc[mi][ni][r] + bv;
    }
  }
}

// ---------------- flash attention ----------------
// r8 structure + r9: 4 blocks/CU (launch_bounds(256,4); LDS 32KB*4=128<=160KB,
// VGPR 104<=128) and XCD-aware flat-grid decode: id&7 selects XCD (HW round-
// robins consecutive ids); each XCD gets 8 whole (b,h) groups (16 q-tiles each)
// so its KV working set is 8*512KB = 4MB = one XCD L2.
__global__ __launch_bounds__(256, 4) void attn_kernel(
    const unsigned short* __restrict__ Qp, const unsigned short* __restrict__ Kp,
    const unsigned short* __restrict__ VTp, unsigned short* __restrict__ Ctx) {
  __shared__ alignas(16) unsigned short Ks[128 * 64];  // Q stage -> K tiles -> P half -> O stage
  __shared__ alignas(16) unsigned short Vt[64 * 128];  // V^T tile (swizzled chunks)

  const int tid = threadIdx.x;
  const int lane = tid & 63, wave = tid >> 6;
  const int lcol = lane & 15, quad = lane >> 4;
  const int wq = wave * 32;
  // XCD-aware decode (bijective on 1024): x=id&7, qt=(id>>3)&15, g=(id>>7)*8+x
  const int id = blockIdx.x;
  const int qt = (id >> 3) & 15;
  const int g = ((id >> 7) << 3) + (id & 7);  // (b,h) group 0..63
  const int b = g >> 4, h = g & 15;
  const size_t bh = (size_t)(b * 16 + h) * 2048 * 64;
  const unsigned short* Qb = Qp + bh + (size_t)qt * 128 * 64;
  const unsigned short* Kb = Kp + bh;
  const unsigned short* VTb = VTp + (size_t)(b * 16 + h) * 64 * 2048;

  // prologue: Q tile into Ks, swizzled; fragments to registers
#pragma unroll
  for (int i = 0; i < 4; ++i) {
    int p = tid + i * 256;
    int row = p >> 3, pj = p & 7;
    load_lds16(Qb + row * 64 + ((pj ^ (row & 7)) * 8), Ks + p * 8);
  }
  __syncthreads();
  short8 qf[2][2];
#pragma unroll
  for (int ni = 0; ni < 2; ++ni)
#pragma unroll
    for (int ks = 0; ks < 2; ++ks) {
      int row = wq + ni * 16 + lcol;
      qf[ni][ks] = *(const short8*)(Ks + row * 64 + (((ks * 4 + quad) ^ (row & 7)) * 8));
    }

  float M[2] = {-1e30f, -1e30f};
  float L[2] = {0.f, 0.f};
  floatx4 Oacc[2][4];
  for (int mi = 0; mi < 2; ++mi)
    for (int nd = 0; nd < 4; ++nd)
      for (int r = 0; r < 4; ++r) Oacc[mi][nd][r] = 0.f;

  for (int jt = 0; jt < 16; ++jt) {
    __syncthreads();  // B0: prev-iter P/V reads done; Ks & Vt free
#pragma unroll
    for (int i = 0; i < 4; ++i) {
      int p = tid + i * 256;
      int kr = p >> 3, kj = p & 7;
      load_lds16(Kb + (size_t)jt * 8192 + kr * 64 + ((kj ^ (kr & 7)) * 8), Ks + p * 8);
      int vr = p >> 4, vj = p & 15;
      load_lds16(VTb + (size_t)vr * 2048 + jt * 128 + ((vj ^ (vr & 7)) * 8), Vt + p * 8);
    }
    __syncthreads();  // B1: tiles visible

    // S^T = K @ Q^T  (Q pre-scaled: sacc already in base-2 logit units)
    floatx4 sacc[8][2];
    for (int mi = 0; mi < 8; ++mi)
      for (int ni = 0; ni < 2; ++ni)
        for (int r = 0; r < 4; ++r) sacc[mi][ni][r] = 0.f;
#pragma unroll
    for (int mi = 0; mi < 8; ++mi) {
      int row = mi * 16 + lcol;
      int sw = (row & 7);
      short8 kf0 = *(const short8*)(Ks + row * 64 + ((quad ^ sw) * 8));
      short8 kf1 = *(const short8*)(Ks + row * 64 + (((4 + quad) ^ sw) * 8));
#pragma unroll
      for (int ni = 0; ni < 2; ++ni) {
        sacc[mi][ni] = __builtin_amdgcn_mfma_f32_16x16x32_bf16(kf0, qf[ni][0], sacc[mi][ni], 0, 0, 0);
        sacc[mi][ni] = __builtin_amdgcn_mfma_f32_16x16x32_bf16(kf1, qf[ni][1], sacc[mi][ni], 0, 0, 0);
      }
    }

    // online softmax over kcol
    float alpha[2];
#pragma unroll
    for (int ni = 0; ni < 2; ++ni) {
      float mx = -1e30f;
#pragma unroll
      for (int mi = 0; mi < 8; ++mi)
#pragma unroll
        for (int r = 0; r < 4; ++r) mx = fmaxf(mx, sacc[mi][ni][r]);
      mx = fmaxf(mx, __shfl_xor(mx, 16));
      mx = fmaxf(mx, __shfl_xor(mx, 32));
      float mnew = fmaxf(M[ni], mx);
      alpha[ni] = exp2f(M[ni] - mnew);
      M[ni] = mnew;
      float rs = 0.f;
#pragma unroll
      for (int mi = 0; mi < 8; ++mi)
#pragma unroll
        for (int r = 0; r < 4; ++r) {
          float p = exp2f(sacc[mi][ni][r] - mnew);
          sacc[mi][ni][r] = p;
          rs += p;
        }
      rs += __shfl_xor(rs, 16);
      rs += __shfl_xor(rs, 32);
      L[ni] = L[ni] * alpha[ni] + rs;
    }
    // rescale O (alpha is quad-uniform; fetch C-layout row's alpha by shuffle)
#pragma unroll
    for (int mi = 0; mi < 2; ++mi)
#pragma unroll
      for (int r = 0; r < 4; ++r) {
        float a = __shfl(alpha[mi], quad * 4 + r);
#pragma unroll
        for (int nd = 0; nd < 4; ++nd) Oacc[mi][nd][r] *= a;
      }

    __syncthreads();  // B2: all waves done reading Ks before P overwrites it

    // P (2 halves of 64 kcols) -> Ks alias; perm-packed writes; fence-ordered
#pragma unroll
    for (int half = 0; half < 2; ++half) {
#pragma unroll
      for (int ni = 0; ni < 2; ++ni) {
        int q = wq + ni * 16 + lcol;
        int sw = q & 7;
#pragma unroll
        for (int m2 = 0; m2 < 4; ++m2) {
          int mi = half * 4 + m2;
          uint2 pw;
          pw.x = pkbf(sacc[mi][ni][1], sacc[mi][ni][0]);
          pw.y = pkbf(sacc[mi][ni][3], sacc[mi][ni][2]);
          int j = 2 * m2 + (quad >> 1);
          *(uint2*)(Ks + q * 64 + ((j ^ sw) * 8) + (quad & 1) * 4) = pw;
        }
      }
      lds_fence();
#pragma unroll
      for (int kk = 0; kk < 2; ++kk) {
        short8 pf[2];
#pragma unroll
        for (int mi = 0; mi < 2; ++mi) {
          int q = wq + mi * 16 + lcol;
          pf[mi] = *(const short8*)(Ks + q * 64 + (((4 * kk + quad) ^ (q & 7)) * 8));
        }
#pragma unroll
        for (int nd = 0; nd < 4; ++nd) {
          int d = nd * 16 + lcol;
          short8 vf = *(const short8*)(Vt + d * 128 + ((((half * 2 + kk) * 4 + quad) ^ (d & 7)) * 8));
#pragma unroll
          for (int mi = 0; mi < 2; ++mi)
            Oacc[mi][nd] = __builtin_amdgcn_mfma_f32_16x16x32_bf16(pf[mi], vf, Oacc[mi][nd], 0, 0, 0);
        }
      }
      lds_fence();
    }
  }

  // epilogue: O/L -> bf16 into Ks (swizzled), then coalesced store
  float linv[2] = {1.f / L[0], 1.f / L[1]};
#pragma unroll
  for (int mi = 0; mi < 2; ++mi)
#pragma unroll
    for (int r = 0; r < 4; ++r) {
      float li = __shfl(linv[mi], quad * 4 + r);
      int q = wq + mi * 16 + quad * 4 + r;
      int sw = q & 7;
#pragma unroll
      for (int nd = 0; nd < 4; ++nd) {
        int j = 2 * nd + (lcol >> 3);
        Ks[q * 64 + ((j ^ sw) * 8) + (lcol & 7)] = f2bf(Oacc[mi][nd][r] * li);
      }
    }
  __syncthreads();
#pragma unroll
  for (int i = 0; i < 4; ++i) {
    int c = tid + i * 256;
    int row = c >> 3, pj = c & 7;
    uint4 v = *(const uint4*)(Ks + row * 64 + ((pj ^ (row & 7)) * 8));
    *(uint4*)(Ctx + ((size_t)(b * 2048 + qt * 128 + row)) * 1024 + h * 64 + pj * 8) = v;
  }
}

// ---------------- launch ----------------
extern "C" void kernel_launch(void* const* d_in, const int* in_sizes, int n_in,
                              void* d_out, int out_size, void* d_ws, size_t ws_size,
                              hipStream_t stream) {
  const float* query = (const float*)d_in[0];
  const float* key_  = (const float*)d_in[1];
  const float* value = (const float*)d_in[2];
  const float* Wq = (const float*)d_in[3];
  const float* bq = (const float*)d_in[4];
  const float* Wk = (const float*)d_in[5];
  const float* bk = (const float*)d_in[6];
  const float* Wv = (const float*)d_in[7];
  const float* bv = (const float*)d_in[8];
  const float* Wo = (const float*)d_in[9];
  const float* bo = (const float*)d_in[10];

  char* w = (char*)d_ws;
  unsigned short* Wb  = (unsigned short*)w; w += (size_t)4 * 1024 * 1024 * 2;  // Wq,Wk,Wv,Wo bf16
  unsigned short* Qp  = (unsigned short*)w; w += (size_t)8192 * 1024 * 2;      // [B,H,S,64]
  unsigned short* Kp  = (unsigned short*)w; w += (size_t)8192 * 1024 * 2;      // [B,H,S,64]
  unsigned short* VTp = (unsigned short*)w; w += (size_t)8192 * 1024 * 2;      // [B,H,64,S]
  unsigned short* Ctx = (unsigned short*)w; w += (size_t)8192 * 1024 * 2;      // [B,S,1024]

  // bf16 activations: query/key park in d_out (dead until gemm_o); value in Ctx slot.
  unsigned short* XqB = (unsigned short*)d_out;
  unsigned short* XkB = (unsigned short*)d_out + (size_t)8192 * 1024;
  unsigned short* XvB = Ctx;

  cvt_all<<<28672, 256, 0, stream>>>(Wq, Wk, Wv, Wo, query, key_, value,
                                     Wb, XqB, XkB, XvB);

  qkv_gemm<<<dim3(8, 64, 3), 256, 0, stream>>>(XqB, XkB, XvB, Wb,
                                               bq, bk, bv, Qp, Kp, VTp);

  attn_kernel<<<1024, 256, 0, stream>>>(Qp, Kp, VTp, Ctx);

  gemm_o<<<dim3(8, 64), 256, 0, stream>>>(Ctx, Wb + (size_t)3 * 1048576, bo, (float*)d_out);
}

// Round 10
// 463.088 us; speedup vs baseline: 1.1646x; 1.1646x over previous
//
#include <hip/hip_runtime.h>
#include <stdint.h>

typedef __attribute__((ext_vector_type(8))) short short8;   // 8 x bf16 MFMA operand
typedef __attribute__((ext_vector_type(4))) float floatx4;  // MFMA accumulator

#define DEV __device__ __forceinline__

DEV unsigned short f2bf(float x) {  // fp32 -> bf16 RNE (epilogue-only; hot paths use pkbf)
  unsigned u = __float_as_uint(x);
  u += 0x7fffu + ((u >> 16) & 1u);
  return (unsigned short)(u >> 16);
}

// pack two fp32 -> two bf16 (round-half-up) in 3 VALU: 2 adds + v_perm
DEV unsigned pkbf(float hi, float lo) {
  return __builtin_amdgcn_perm(__float_as_uint(hi) + 0x8000u,
                               __float_as_uint(lo) + 0x8000u, 0x07060302u);
}

DEV void load_lds16(const unsigned short* g, unsigned short* l) {
  __builtin_amdgcn_global_load_lds(
      (const __attribute__((address_space(1))) void*)g,
      (__attribute__((address_space(3))) void*)l, 16, 0, 0);
}

DEV void lds_fence() { asm volatile("" ::: "memory"); }  // wave-private LDS RAW/WAR ordering

// ---------------- one-shot fp32 -> bf16 of all 7 tensors ----------------
__global__ void cvt_all(const float* __restrict__ Wq, const float* __restrict__ Wk,
                        const float* __restrict__ Wv, const float* __restrict__ Wo,
                        const float* __restrict__ Xq, const float* __restrict__ Xk,
                        const float* __restrict__ Xv,
                        unsigned short* __restrict__ Wb, unsigned short* __restrict__ XqB,
                        unsigned short* __restrict__ XkB, unsigned short* __restrict__ XvB) {
  int bid = blockIdx.x;
  const float* src;
  unsigned short* dst;
  int off;
  if (bid < 4096) {
    int sel = bid >> 10;
    src = sel == 0 ? Wq : sel == 1 ? Wk : sel == 2 ? Wv : Wo;
    dst = Wb + (size_t)sel * 1048576;
    off = bid & 1023;
  } else {
    bid -= 4096;
    int sel = bid >> 13;
    src = sel == 0 ? Xq : sel == 1 ? Xk : Xv;
    dst = sel == 0 ? XqB : sel == 1 ? XkB : XvB;
    off = bid & 8191;
  }
  int i = (off * 256 + threadIdx.x) * 4;
  float4 v = *(const float4*)(src + i);
  uint2 o;
  o.x = pkbf(v.y, v.x);
  o.y = pkbf(v.w, v.z);
  *(uint2*)(dst + i) = o;
}

// ---------------- fused QKV projection: all-bf16 async staging, grid (8,64,3) ----------------
// z=0: Qp[b,h,s,64] = (q@Wq^T+bq) * SCQ   z=1: Kp = k@Wk^T+bk
// z=2: VTp[b,h,64,s] = (v@Wv^T+bv)^T (A/B operand roles swapped)
#define SCQ (0.125f * 1.44269504089f)
__global__ __launch_bounds__(256, 3) void qkv_gemm(
    const unsigned short* __restrict__ XqB, const unsigned short* __restrict__ XkB,
    const unsigned short* __restrict__ XvB,
    const unsigned short* __restrict__ Wb,
    const float* __restrict__ bq, const float* __restrict__ bk, const float* __restrict__ bv,
    unsigned short* __restrict__ Qp, unsigned short* __restrict__ Kp,
    unsigned short* __restrict__ VTp) {
  __shared__ alignas(16) unsigned short Xs[128 * 32];
  __shared__ alignas(16) unsigned short Ws[128 * 32];
  const int z = blockIdx.z;
  const unsigned short* X = z == 0 ? XqB : z == 1 ? XkB : XvB;
  const unsigned short* W = Wb + (size_t)z * 1048576;
  const float* bias = z == 0 ? bq : z == 1 ? bk : bv;

  const int tid = threadIdx.x;
  const int lane = tid & 63, wave = tid >> 6;
  const int lcol = lane & 15, quad = lane >> 4;
  const int wo = blockIdx.x * 128;  // d origin (weight rows)
  const int xo = blockIdx.y * 128;  // s origin (input rows)
  const int wm = (wave & 1) * 64;
  const int wn = (wave >> 1) * 64;

  floatx4 acc[4][4];
  for (int mi = 0; mi < 4; ++mi)
    for (int ni = 0; ni < 4; ++ni)
      for (int r = 0; r < 4; ++r) acc[mi][ni][r] = 0.f;

  const unsigned short* Abuf = (z < 2) ? Xs : Ws;  // MFMA A operand rows (m)
  const unsigned short* Bbuf = (z < 2) ? Ws : Xs;  // MFMA B operand rows (n)

  for (int kt = 0; kt < 32; ++kt) {
    const int k0 = kt * 32;
    int c = tid;
    load_lds16(W + (size_t)(wo + (c >> 2)) * 1024 + k0 + (c & 3) * 8, Ws + c * 8);
    load_lds16(X + (size_t)(xo + (c >> 2)) * 1024 + k0 + (c & 3) * 8, Xs + c * 8);
    c = tid + 256;
    load_lds16(W + (size_t)(wo + (c >> 2)) * 1024 + k0 + (c & 3) * 8, Ws + c * 8);
    load_lds16(X + (size_t)(xo + (c >> 2)) * 1024 + k0 + (c & 3) * 8, Xs + c * 8);
    __syncthreads();
    short8 af[4], bf[4];
#pragma unroll
    for (int mi = 0; mi < 4; ++mi)
      af[mi] = *(const short8*)(Abuf + (wm + mi * 16 + lcol) * 32 + quad * 8);
#pragma unroll
    for (int ni = 0; ni < 4; ++ni)
      bf[ni] = *(const short8*)(Bbuf + (wn + ni * 16 + lcol) * 32 + quad * 8);
#pragma unroll
    for (int mi = 0; mi < 4; ++mi)
#pragma unroll
      for (int ni = 0; ni < 4; ++ni)
        acc[mi][ni] = __builtin_amdgcn_mfma_f32_16x16x32_bf16(af[mi], bf[ni], acc[mi][ni], 0, 0, 0);
    __syncthreads();
  }

  if (z < 2) {  // C[m=s][n=d] -> head-split [B,H,S,64]
    unsigned short* Out = z == 0 ? Qp : Kp;
    const float scl = z == 0 ? SCQ : 1.f;
#pragma unroll
    for (int ni = 0; ni < 4; ++ni) {
      int col = wo + wn + ni * 16 + lcol;
      float bvx = bias[col];
      int h = col >> 6, d = col & 63;
#pragma unroll
      for (int mi = 0; mi < 4; ++mi) {
        int rbase = xo + wm + mi * 16 + quad * 4;
#pragma unroll
        for (int r = 0; r < 4; ++r) {
          int grow = rbase + r;            // = b*2048 + s
          int bb = grow >> 11, s = grow & 2047;
          Out[((size_t)(bb * 16 + h) * 2048 + s) * 64 + d] = f2bf((acc[mi][ni][r] + bvx) * scl);
        }
      }
    }
  } else {  // C[m=d][n=s] -> V^T [B,H,64,S]
#pragma unroll
    for (int mi = 0; mi < 4; ++mi) {
      int dbase = wo + wm + mi * 16 + quad * 4;
#pragma unroll
      for (int r = 0; r < 4; ++r) {
        int dg = dbase + r;
        float bvx = bias[dg];
        int h = dg >> 6, dk = dg & 63;
#pragma unroll
        for (int ni = 0; ni < 4; ++ni) {
          int sg = xo + wn + ni * 16 + lcol;  // = b*2048 + s
          int bb = sg >> 11, ss = sg & 2047;
          VTp[((size_t)(bb * 16 + h) * 64 + dk) * 2048 + ss] = f2bf(acc[mi][ni][r] + bvx);
        }
      }
    }
  }
}

// ---------------- final O-projection: fp32 out ----------------
__global__ __launch_bounds__(256, 3) void gemm_o(
    const unsigned short* __restrict__ A, const unsigned short* __restrict__ Bw,
    const float* __restrict__ bias, float* __restrict__ Out) {
  __shared__ alignas(16) unsigned short As[128 * 32];
  __shared__ alignas(16) unsigned short Bs[128 * 32];
  const int tid = threadIdx.x;
  const int lane = tid & 63, wave = tid >> 6;
  const int lcol = lane & 15, quad = lane >> 4;
  const int n0 = blockIdx.x * 128;
  const int m0 = blockIdx.y * 128;
  const int wm = (wave & 1) * 64;
  const int wn = (wave >> 1) * 64;

  floatx4 acc[4][4];
  for (int mi = 0; mi < 4; ++mi)
    for (int ni = 0; ni < 4; ++ni)
      for (int r = 0; r < 4; ++r) acc[mi][ni][r] = 0.f;

  for (int kt = 0; kt < 32; ++kt) {
    const int k0 = kt * 32;
    int c = tid;
    load_lds16(Bw + (size_t)(n0 + (c >> 2)) * 1024 + k0 + (c & 3) * 8, Bs + c * 8);
    load_lds16(A  + (size_t)(m0 + (c >> 2)) * 1024 + k0 + (c & 3) * 8, As + c * 8);
    c = tid + 256;
    load_lds16(Bw + (size_t)(n0 + (c >> 2)) * 1024 + k0 + (c & 3) * 8, Bs + c * 8);
    load_lds16(A  + (size_t)(m0 + (c >> 2)) * 1024 + k0 + (c & 3) * 8, As + c * 8);
    __syncthreads();
    short8 af[4], bf[4];
#pragma unroll
    for (int mi = 0; mi < 4; ++mi)
      af[mi] = *(const short8*)(As + (wm + mi * 16 + lcol) * 32 + quad * 8);
#pragma unroll
    for (int ni = 0; ni < 4; ++ni)
      bf[ni] = *(const short8*)(Bs + (wn + ni * 16 + lcol) * 32 + quad * 8);
#pragma unroll
    for (int mi = 0; mi < 4; ++mi)
#pragma unroll
      for (int ni = 0; ni < 4; ++ni)
        acc[mi][ni] = __builtin_amdgcn_mfma_f32_16x16x32_bf16(af[mi], bf[ni], acc[mi][ni], 0, 0, 0);
    __syncthreads();
  }
#pragma unroll
  for (int ni = 0; ni < 4; ++ni) {
    int col = n0 + wn + ni * 16 + lcol;
    float bv = bias[col];
#pragma unroll
    for (int mi = 0; mi < 4; ++mi) {
      int rbase = m0 + wm + mi * 16 + quad * 4;
#pragma unroll
      for (int r = 0; r < 4; ++r)
        Out[(size_t)(rbase + r) * 1024 + col] = acc[mi][ni][r] + bv;
    }
  }
}

// ---------------- flash attention ----------------
// r8 structure + XCD swizzle. Occupancy: launch_bounds(256,3) -> VGPR budget
// ~170 >= 104 actual (NO spill; r9's (256,4) forced 64 VGPR + 540MB scratch
// traffic, MfmaUtil 0.5%), 3 blocks/CU, LDS 3x32KB=96<=160KB.
__global__ __launch_bounds__(256, 3) void attn_kernel(
    const unsigned short* __restrict__ Qp, const unsigned short* __restrict__ Kp,
    const unsigned short* __restrict__ VTp, unsigned short* __restrict__ Ctx) {
  __shared__ alignas(16) unsigned short Ks[128 * 64];  // Q stage -> K tiles -> P half -> O stage
  __shared__ alignas(16) unsigned short Vt[64 * 128];  // V^T tile (swizzled chunks)

  const int tid = threadIdx.x;
  const int lane = tid & 63, wave = tid >> 6;
  const int lcol = lane & 15, quad = lane >> 4;
  const int wq = wave * 32;
  // XCD-aware decode (bijective on 1024): x=id&7 -> XCD; each XCD gets 8 whole
  // (b,h) groups so its KV working set is 8*512KB = 4MB = one XCD L2.
  const int id = blockIdx.x;
  const int qt = (id >> 3) & 15;
  const int g = ((id >> 7) << 3) + (id & 7);  // (b,h) group 0..63
  const int b = g >> 4, h = g & 15;
  const size_t bh = (size_t)(b * 16 + h) * 2048 * 64;
  const unsigned short* Qb = Qp + bh + (size_t)qt * 128 * 64;
  const unsigned short* Kb = Kp + bh;
  const unsigned short* VTb = VTp + (size_t)(b * 16 + h) * 64 * 2048;

  // prologue: Q tile into Ks, swizzled; fragments to registers
#pragma unroll
  for (int i = 0; i < 4; ++i) {
    int p = tid + i * 256;
    int row = p >> 3, pj = p & 7;
    load_lds16(Qb + row * 64 + ((pj ^ (row & 7)) * 8), Ks + p * 8);
  }
  __syncthreads();
  short8 qf[2][2];
#pragma unroll
  for (int ni = 0; ni < 2; ++ni)
#pragma unroll
    for (int ks = 0; ks < 2; ++ks) {
      int row = wq + ni * 16 + lcol;
      qf[ni][ks] = *(const short8*)(Ks + row * 64 + (((ks * 4 + quad) ^ (row & 7)) * 8));
    }

  float M[2] = {-1e30f, -1e30f};
  float L[2] = {0.f, 0.f};
  floatx4 Oacc[2][4];
  for (int mi = 0; mi < 2; ++mi)
    for (int nd = 0; nd < 4; ++nd)
      for (int r = 0; r < 4; ++r) Oacc[mi][nd][r] = 0.f;

  for (int jt = 0; jt < 16; ++jt) {
    __syncthreads();  // B0: prev-iter P/V reads done; Ks & Vt free
#pragma unroll
    for (int i = 0; i < 4; ++i) {
      int p = tid + i * 256;
      int kr = p >> 3, kj = p & 7;
      load_lds16(Kb + (size_t)jt * 8192 + kr * 64 + ((kj ^ (kr & 7)) * 8), Ks + p * 8);
      int vr = p >> 4, vj = p & 15;
      load_lds16(VTb + (size_t)vr * 2048 + jt * 128 + ((vj ^ (vr & 7)) * 8), Vt + p * 8);
    }
    __syncthreads();  // B1: tiles visible

    // S^T = K @ Q^T  (Q pre-scaled: sacc already in base-2 logit units)
    floatx4 sacc[8][2];
    for (int mi = 0; mi < 8; ++mi)
      for (int ni = 0; ni < 2; ++ni)
        for (int r = 0; r < 4; ++r) sacc[mi][ni][r] = 0.f;
#pragma unroll
    for (int mi = 0; mi < 8; ++mi) {
      int row = mi * 16 + lcol;
      int sw = (row & 7);
      short8 kf0 = *(const short8*)(Ks + row * 64 + ((quad ^ sw) * 8));
      short8 kf1 = *(const short8*)(Ks + row * 64 + (((4 + quad) ^ sw) * 8));
#pragma unroll
      for (int ni = 0; ni < 2; ++ni) {
        sacc[mi][ni] = __builtin_amdgcn_mfma_f32_16x16x32_bf16(kf0, qf[ni][0], sacc[mi][ni], 0, 0, 0);
        sacc[mi][ni] = __builtin_amdgcn_mfma_f32_16x16x32_bf16(kf1, qf[ni][1], sacc[mi][ni], 0, 0, 0);
      }
    }

    // online softmax over kcol
    float alpha[2];
#pragma unroll
    for (int ni = 0; ni < 2; ++ni) {
      float mx = -1e30f;
#pragma unroll
      for (int mi = 0; mi < 8; ++mi)
#pragma unroll
        for (int r = 0; r < 4; ++r) mx = fmaxf(mx, sacc[mi][ni][r]);
      mx = fmaxf(mx, __shfl_xor(mx, 16));
      mx = fmaxf(mx, __shfl_xor(mx, 32));
      float mnew = fmaxf(M[ni], mx);
      alpha[ni] = exp2f(M[ni] - mnew);
      M[ni] = mnew;
      float rs = 0.f;
#pragma unroll
      for (int mi = 0; mi < 8; ++mi)
#pragma unroll
        for (int r = 0; r < 4; ++r) {
          float p = exp2f(sacc[mi][ni][r] - mnew);
          sacc[mi][ni][r] = p;
          rs += p;
        }
      rs += __shfl_xor(rs, 16);
      rs += __shfl_xor(rs, 32);
      L[ni] = L[ni] * alpha[ni] + rs;
    }
    // rescale O (alpha is quad-uniform; fetch C-layout row's alpha by shuffle)
#pragma unroll
    for (int mi = 0; mi < 2; ++mi)
#pragma unroll
      for (int r = 0; r < 4; ++r) {
        float a = __shfl(alpha[mi], quad * 4 + r);
#pragma unroll
        for (int nd = 0; nd < 4; ++nd) Oacc[mi][nd][r] *= a;
      }

    __syncthreads();  // B2: all waves done reading Ks before P overwrites it

    // P (2 halves of 64 kcols) -> Ks alias; perm-packed writes; fence-ordered
#pragma unroll
    for (int half = 0; half < 2; ++half) {
#pragma unroll
      for (int ni = 0; ni < 2; ++ni) {
        int q = wq + ni * 16 + lcol;
        int sw = q & 7;
#pragma unroll
        for (int m2 = 0; m2 < 4; ++m2) {
          int mi = half * 4 + m2;
          uint2 pw;
          pw.x = pkbf(sacc[mi][ni][1], sacc[mi][ni][0]);
          pw.y = pkbf(sacc[mi][ni][3], sacc[mi][ni][2]);
          int j = 2 * m2 + (quad >> 1);
          *(uint2*)(Ks + q * 64 + ((j ^ sw) * 8) + (quad & 1) * 4) = pw;
        }
      }
      lds_fence();
#pragma unroll
      for (int kk = 0; kk < 2; ++kk) {
        short8 pf[2];
#pragma unroll
        for (int mi = 0; mi < 2; ++mi) {
          int q = wq + mi * 16 + lcol;
          pf[mi] = *(const short8*)(Ks + q * 64 + (((4 * kk + quad) ^ (q & 7)) * 8));
        }
#pragma unroll
        for (int nd = 0; nd < 4; ++nd) {
          int d = nd * 16 + lcol;
          short8 vf = *(const short8*)(Vt + d * 128 + ((((half * 2 + kk) * 4 + quad) ^ (d & 7)) * 8));
#pragma unroll
          for (int mi = 0; mi < 2; ++mi)
            Oacc[mi][nd] = __builtin_amdgcn_mfma_f32_16x16x32_bf16(pf[mi], vf, Oacc[mi][nd], 0, 0, 0);
        }
      }
      lds_fence();
    }
  }

  // epilogue: O/L -> bf16 into Ks (swizzled), then coalesced store
  float linv[2] = {1.f / L[0], 1.f / L[1]};
#pragma unroll
  for (int mi = 0; mi < 2; ++mi)
#pragma unroll
    for (int r = 0; r < 4; ++r) {
      float li = __shfl(linv[mi], quad * 4 + r);
      int q = wq + mi * 16 + quad * 4 + r;
      int sw = q & 7;
#pragma unroll
      for (int nd = 0; nd < 4; ++nd) {
        int j = 2 * nd + (lcol >> 3);
        Ks[q * 64 + ((j ^ sw) * 8) + (lcol & 7)] = f2bf(Oacc[mi][nd][r] * li);
      }
    }
  __syncthreads();
#pragma unroll
  for (int i = 0; i < 4; ++i) {
    int c = tid + i * 256;
    int row = c >> 3, pj = c & 7;
    uint4 v = *(const uint4*)(Ks + row * 64 + ((pj ^ (row & 7)) * 8));
    *(uint4*)(Ctx + ((size_t)(b * 2048 + qt * 128 + row)) * 1024 + h * 64 + pj * 8) = v;
  }
}

// ---------------- launch ----------------
extern "C" void kernel_launch(void* const* d_in, const int* in_sizes, int n_in,
                              void* d_out, int out_size, void* d_ws, size_t ws_size,
                              hipStream_t stream) {
  const float* query = (const float*)d_in[0];
  const float* key_  = (const float*)d_in[1];
  const float* value = (const float*)d_in[2];
  const float* Wq = (const float*)d_in[3];
  const float* bq = (const float*)d_in[4];
  const float* Wk = (const float*)d_in[5];
  const float* bk = (const float*)d_in[6];
  const float* Wv = (const float*)d_in[7];
  const float* bv = (const float*)d_in[8];
  const float* Wo = (const float*)d_in[9];
  const float* bo = (const float*)d_in[10];

  char* w = (char*)d_ws;
  unsigned short* Wb  = (unsigned short*)w; w += (size_t)4 * 1024 * 1024 * 2;  // Wq,Wk,Wv,Wo bf16
  unsigned short* Qp  = (unsigned short*)w; w += (size_t)8192 * 1024 * 2;      // [B,H,S,64]
  unsigned short* Kp  = (unsigned short*)w; w += (size_t)8192 * 1024 * 2;      // [B,H,S,64]
  unsigned short* VTp = (unsigned short*)w; w += (size_t)8192 * 1024 * 2;      // [B,H,64,S]
  unsigned short* Ctx = (unsigned short*)w; w += (size_t)8192 * 1024 * 2;      // [B,S,1024]

  // bf16 activations: query/key park in d_out (dead until gemm_o); value in Ctx slot.
  unsigned short* XqB = (unsigned short*)d_out;
  unsigned short* XkB = (unsigned short*)d_out + (size_t)8192 * 1024;
  unsigned short* XvB = Ctx;

  cvt_all<<<28672, 256, 0, stream>>>(Wq, Wk, Wv, Wo, query, key_, value,
                                     Wb, XqB, XkB, XvB);

  qkv_gemm<<<dim3(8, 64, 3), 256, 0, stream>>>(XqB, XkB, XvB, Wb,
                                               bq, bk, bv, Qp, Kp, VTp);

  attn_kernel<<<1024, 256, 0, stream>>>(Qp, Kp, VTp, Ctx);

  gemm_o<<<dim3(8, 64), 256, 0, stream>>>(Ctx, Wb + (size_t)3 * 1048576, bo, (float*)d_out);
}